// Round 1
// baseline (38497.931 us; speedup 1.0000x reference)
//
#include <hip/hip_runtime.h>
#include <hip/hip_fp16.h>

#define BB 32
#define TIN 1024
#define FIN 80
#define CC 512
#define UU 512
#define GG 1536
#define VV 1024
#define TT 512
#define MM (BB*TT)   // 16384
#define EPS 1e-3f
#define NWDIR 128    // workgroups per direction in recurrence

// ---------------- conv1d(stride2,SAME) + bias + relu + BN -> f16 ----------------
__global__ __launch_bounds__(256) void conv_bn_k(
    const float* __restrict__ x, const float* __restrict__ w, const float* __restrict__ cb,
    const float* __restrict__ gam, const float* __restrict__ bet,
    const float* __restrict__ mu_, const float* __restrict__ var_,
    __half* __restrict__ out)
{
  __shared__ float xs[41*80];
  int tg = blockIdx.x;        // 32 groups of 16 t
  int b  = blockIdx.y;
  int ch = blockIdx.z;        // 0/1 channel half
  int t0 = tg*16;
  int in0 = t0*2 - 4;         // SAME pad_left = 4 (pad_total 9)
  for (int i = threadIdx.x; i < 41*80; i += 256) {
    int r = i / 80, f = i - r*80;
    int ri = in0 + r;
    xs[i] = (ri >= 0 && ri < TIN) ? x[((size_t)b*TIN + ri)*FIN + f] : 0.f;
  }
  __syncthreads();
  int c = ch*256 + threadIdx.x;
  float acc[16];
  float bv = cb[c];
#pragma unroll
  for (int i = 0; i < 16; i++) acc[i] = bv;
  for (int k = 0; k < 11; k++) {
    for (int f = 0; f < 80; f++) {
      float wv = w[((size_t)k*80 + f)*CC + c];
#pragma unroll
      for (int i = 0; i < 16; i++) acc[i] += xs[(2*i + k)*80 + f] * wv;
    }
  }
  float ga = gam[c], be = bet[c], mu = mu_[c], iv = rsqrtf(var_[c] + EPS);
#pragma unroll
  for (int i = 0; i < 16; i++) {
    float v = fmaxf(acc[i], 0.f);
    out[((size_t)b*TT + t0 + i)*CC + c] = __float2half(ga*(v - mu)*iv + be);
  }
}

// ---------------- fp32 SGEMM: C(M,N) = op(A)(M,K) @ Bw(K,N) + bias ----------------
// MODE 0: A = A0 ; MODE 1: A = A0+A1 ; MODE 2: A = BN(A0+A1). A stored f16.
// OUTHALF 1: write __half ; 0: write float.
template<int MODE, int OUTHALF>
__global__ __launch_bounds__(256) void sgemm_k(
    const __half* __restrict__ A0, const __half* __restrict__ A1,
    const float* __restrict__ gam, const float* __restrict__ bet,
    const float* __restrict__ mu_, const float* __restrict__ var_,
    const float* __restrict__ Bw, const float* __restrict__ bias,
    void* __restrict__ Cout, int M, int N, int K)
{
  __shared__ float As[8][128];
  __shared__ float Bs[8][128];
  int row0 = blockIdx.y * 128;
  int col0 = blockIdx.x * 128;
  int tid = threadIdx.x;
  int tx = tid & 15, ty = tid >> 4;
  float acc[8][8];
#pragma unroll
  for (int i=0;i<8;i++)
#pragma unroll
    for (int j=0;j<8;j++) acc[i][j]=0.f;
  int ar = tid >> 1;
  int akq = (tid & 1)*4;
  int bkr = tid >> 5;
  int bc = (tid & 31)*4;
  for (int k0 = 0; k0 < K; k0 += 8) {
    size_t aoff = (size_t)(row0+ar)*K + k0 + akq;
    float2 lo = __half22float2(*(const __half2*)(A0 + aoff));
    float2 hi = __half22float2(*(const __half2*)(A0 + aoff + 2));
    float4 a; a.x=lo.x; a.y=lo.y; a.z=hi.x; a.w=hi.y;
    if (MODE >= 1) {
      float2 l1 = __half22float2(*(const __half2*)(A1 + aoff));
      float2 h1 = __half22float2(*(const __half2*)(A1 + aoff + 2));
      a.x+=l1.x; a.y+=l1.y; a.z+=h1.x; a.w+=h1.y;
    }
    if (MODE == 2) {
      int kk = k0 + akq;
      float4 g4 = *(const float4*)(gam+kk);
      float4 b4 = *(const float4*)(bet+kk);
      float4 m4 = *(const float4*)(mu_+kk);
      float4 v4 = *(const float4*)(var_+kk);
      a.x = g4.x*(a.x-m4.x)*rsqrtf(v4.x+EPS)+b4.x;
      a.y = g4.y*(a.y-m4.y)*rsqrtf(v4.y+EPS)+b4.y;
      a.z = g4.z*(a.z-m4.z)*rsqrtf(v4.z+EPS)+b4.z;
      a.w = g4.w*(a.w-m4.w)*rsqrtf(v4.w+EPS)+b4.w;
    }
    As[akq+0][ar]=a.x; As[akq+1][ar]=a.y; As[akq+2][ar]=a.z; As[akq+3][ar]=a.w;
    *(float4*)&Bs[bkr][bc] = *(const float4*)(Bw + (size_t)(k0+bkr)*N + col0 + bc);
    __syncthreads();
#pragma unroll
    for (int kk = 0; kk < 8; kk++) {
      float ar8[8], br8[8];
      *(float4*)&ar8[0] = *(const float4*)&As[kk][ty*8];
      *(float4*)&ar8[4] = *(const float4*)&As[kk][ty*8+4];
      *(float4*)&br8[0] = *(const float4*)&Bs[kk][tx*8];
      *(float4*)&br8[4] = *(const float4*)&Bs[kk][tx*8+4];
#pragma unroll
      for (int i=0;i<8;i++)
#pragma unroll
        for (int j=0;j<8;j++) acc[i][j] += ar8[i]*br8[j];
    }
    __syncthreads();
  }
#pragma unroll
  for (int i=0;i<8;i++) {
    int r = row0 + ty*8 + i;
#pragma unroll
    for (int j=0;j<8;j++) {
      int c2 = col0 + tx*8 + j;
      float v = acc[i][j] + bias[c2];
      if (OUTHALF) ((__half*)Cout)[(size_t)r*N + c2] = __float2half(v);
      else         ((float*)Cout)[(size_t)r*N + c2] = v;
    }
  }
}

// ---------------- persistent bidirectional GRU layer ----------------
// grid = 256 blocks (128 per direction), 256 threads, one block per CU.
// WG wg owns u-slice [wg*4, wg*4+4). Per step: team barrier -> stage h (LDS)
// -> rg = h @ Wh_slice (fp32) -> gates -> write h slice + hs output.
__global__ __launch_bounds__(256) void gru_layer_k(
    const __half* __restrict__ xgf, const __half* __restrict__ xgb,
    const float* __restrict__ whf, const float* __restrict__ whb,
    const float* __restrict__ brf, const float* __restrict__ brb,
    __half* __restrict__ hsf, __half* __restrict__ hsb,
    float* __restrict__ hping, unsigned int* __restrict__ cnt)
{
  int wg  = blockIdx.x & (NWDIR-1);
  int dir = blockIdx.x >> 7;
  const __half* xg = dir ? xgb : xgf;
  const float* wh  = dir ? whb : whf;
  const float* brc = dir ? brb : brf;
  __half* hs = dir ? hsb : hsf;
  float* hb0 = hping + (size_t)dir * 2 * 32 * 512;   // two ping-pong buffers [b][k]
  unsigned int* c = cnt + dir;
  int tid = threadIdx.x;
  int u0 = wg * 4;

  __shared__ float Whs[12][516];   // [g*4+uu][k], padded
  __shared__ float hsl[32][512];   // h staged, xor-swizzled by (b>>2)
  __shared__ float S[8][12][33];   // k-partials [kh][col][b]

  for (int i = tid; i < 12*512; i += 256) {
    int cq = i >> 9;
    int k  = i & 511;
    int gcol = (cq>>2)*512 + u0 + (cq&3);
    Whs[cq][k] = wh[(size_t)k*GG + gcol];
  }
  int gb = tid & 31, guu = (tid >> 5) & 3;   // gate-phase mapping (tid<128)
  float brz=0.f, brr=0.f, brh=0.f, hreg=0.f;
  if (tid < 128) {
    int u = u0 + guu;
    brz = brc[u]; brr = brc[512+u]; brh = brc[1024+u];
    hb0[gb*512 + u] = 0.f;                   // zero ping buffer 0 (h0 = 0)
  }
  int bq = tid & 7, uu = (tid>>3)&3, kh = tid>>5;  // matmul mapping
  int k0 = kh*64;
  int xorc = bq << 2;

  for (int s = 0; s < 512; s++) {
    __syncthreads();   // drains all global stores of prev step (vmcnt0 before barrier)
    if (tid == 0) {
      __hip_atomic_fetch_add(c, 1u, __ATOMIC_RELEASE, __HIP_MEMORY_SCOPE_AGENT);
      unsigned int tgt = (unsigned int)(s+1) * NWDIR;
      long guard = 0;
      while (__hip_atomic_load(c, __ATOMIC_RELAXED, __HIP_MEMORY_SCOPE_AGENT) < tgt) {
        if (++guard > 20000000L) break;      // deadlock bailout (wrong answer, no hang)
      }
    }
    __syncthreads();
    __threadfence();   // acquire: invalidate L1/L2 so h reads are fresh
    int p = s & 1;
    const float* hp = hb0 + p*32*512;
    for (int i = tid; i < 4096; i += 256) {
      float4 v = ((const float4*)hp)[i];
      int b = i >> 7;
      int k = (i & 127) << 2;
      *(float4*)&hsl[b][k ^ ((b>>2)<<2)] = v;
    }
    __syncthreads();
    float a0[4] = {0,0,0,0}, a1[4] = {0,0,0,0}, a2[4] = {0,0,0,0};
#pragma unroll 4
    for (int k4 = 0; k4 < 64; k4 += 4) {
      int kk = k0 + k4;
      float4 w0 = *(const float4*)&Whs[uu  ][kk];
      float4 w1 = *(const float4*)&Whs[4+uu][kk];
      float4 w2 = *(const float4*)&Whs[8+uu][kk];
#pragma unroll
      for (int bi = 0; bi < 4; bi++) {
        float4 hv = *(const float4*)&hsl[bq*4+bi][kk ^ xorc];
        a0[bi] += w0.x*hv.x + w0.y*hv.y + w0.z*hv.z + w0.w*hv.w;
        a1[bi] += w1.x*hv.x + w1.y*hv.y + w1.z*hv.z + w1.w*hv.w;
        a2[bi] += w2.x*hv.x + w2.y*hv.y + w2.z*hv.z + w2.w*hv.w;
      }
    }
#pragma unroll
    for (int bi = 0; bi < 4; bi++) {
      S[kh][uu  ][bq*4+bi] = a0[bi];
      S[kh][4+uu][bq*4+bi] = a1[bi];
      S[kh][8+uu][bq*4+bi] = a2[bi];
    }
    __syncthreads();
    if (tid < 128) {
      int u = u0 + guu;
      int t = dir ? (511 - s) : s;
      float rz = brz, rr = brr, rh = brh;
#pragma unroll
      for (int q = 0; q < 8; q++) {
        rz += S[q][guu  ][gb];
        rr += S[q][4+guu][gb];
        rh += S[q][8+guu][gb];
      }
      const __half* xp = xg + ((size_t)gb*TT + t)*GG;
      float xz = __half2float(xp[u]);
      float xr = __half2float(xp[512+u]);
      float xh = __half2float(xp[1024+u]);
      float z = 1.f/(1.f + __expf(-(xz + rz)));
      float r = 1.f/(1.f + __expf(-(xr + rr)));
      float hh = fmaxf(xh + r*rh, 0.f);
      float hn = z*hreg + (1.f - z)*hh;
      hreg = hn;
      hb0[(1-p)*32*512 + gb*512 + u] = hn;             // publish for team
      hs[((size_t)gb*TT + t)*UU + u] = __float2half(hn); // sequence output
    }
  }
}

// ---------------- row softmax over V=1024, in place ----------------
__global__ __launch_bounds__(256) void softmax_k(float* __restrict__ p) {
  size_t row = blockIdx.x;
  float* pr = p + row*VV;
  int tid = threadIdx.x;
  float4 v = ((float4*)pr)[tid];
  float m = fmaxf(fmaxf(v.x, v.y), fmaxf(v.z, v.w));
#pragma unroll
  for (int o = 32; o >= 1; o >>= 1) m = fmaxf(m, __shfl_xor(m, o));
  __shared__ float red[4];
  __shared__ float red2[4];
  int w = tid >> 6;
  if ((tid & 63) == 0) red[w] = m;
  __syncthreads();
  m = fmaxf(fmaxf(red[0], red[1]), fmaxf(red[2], red[3]));
  v.x = __expf(v.x - m); v.y = __expf(v.y - m);
  v.z = __expf(v.z - m); v.w = __expf(v.w - m);
  float s = v.x + v.y + v.z + v.w;
#pragma unroll
  for (int o = 32; o >= 1; o >>= 1) s += __shfl_xor(s, o);
  if ((tid & 63) == 0) red2[w] = s;
  __syncthreads();
  s = red2[0] + red2[1] + red2[2] + red2[3];
  float inv = 1.f / s;
  v.x *= inv; v.y *= inv; v.z *= inv; v.w *= inv;
  ((float4*)pr)[tid] = v;
}

extern "C" void kernel_launch(void* const* d_in, const int* in_sizes, int n_in,
                              void* d_out, int out_size, void* d_ws, size_t ws_size,
                              hipStream_t stream) {
  const float* x      = (const float*)d_in[0];
  const float* conv_w = (const float*)d_in[1];
  const float* conv_b = (const float*)d_in[2];
  const float* wx_f   = (const float*)d_in[3];
  const float* wh_f   = (const float*)d_in[4];
  const float* bi_f   = (const float*)d_in[5];
  const float* br_f   = (const float*)d_in[6];
  const float* wx_b   = (const float*)d_in[7];
  const float* wh_b   = (const float*)d_in[8];
  const float* bi_b   = (const float*)d_in[9];
  const float* br_b   = (const float*)d_in[10];
  const float* gam    = (const float*)d_in[11];
  const float* bet    = (const float*)d_in[12];
  const float* mu_    = (const float*)d_in[13];
  const float* var_   = (const float*)d_in[14];
  const float* dw     = (const float*)d_in[15];
  const float* db     = (const float*)d_in[16];

  char* ws = (char*)d_ws;
  // layout (bytes)
  __half* c0   = (__half*)(ws + 0);                 // 16,777,216  (conv/BN out; later hs2_f)
  __half* xgf  = (__half*)(ws + 16777216LL);        // 50,331,648
  __half* xgb  = (__half*)(ws + 67108864LL);        // 50,331,648
  __half* hs1f = (__half*)(ws + 117440512LL);       // 16,777,216  (later hs2_b)
  __half* hs1b = (__half*)(ws + 134217728LL);       // 16,777,216
  float*  hping = (float*)(ws + 150994944LL);       // 262,144
  unsigned int* cnt = (unsigned int*)(ws + 151257088LL); // 64
  if (ws_size < 151257152ULL) return;               // fail clean rather than corrupt
  __half* hs2f = c0;
  __half* hs2b = hs1f;
  float* logits = (float*)d_out;

  hipMemsetAsync(cnt, 0, 64, stream);               // barrier counters (4 used)

  dim3 cg(32, 32, 2);
  conv_bn_k<<<cg, 256, 0, stream>>>(x, conv_w, conv_b, gam, bet, mu_, var_, c0);

  dim3 g1(12, 128);  // N/128, M/128 for N=1536
  sgemm_k<0,1><<<g1, 256, 0, stream>>>(c0, nullptr, nullptr,nullptr,nullptr,nullptr,
                                       wx_f, bi_f, xgf, MM, GG, CC);
  sgemm_k<0,1><<<g1, 256, 0, stream>>>(c0, nullptr, nullptr,nullptr,nullptr,nullptr,
                                       wx_b, bi_b, xgb, MM, GG, CC);
  gru_layer_k<<<256, 256, 0, stream>>>(xgf, xgb, wh_f, wh_b, br_f, br_b,
                                       hs1f, hs1b, hping, cnt);
  sgemm_k<1,1><<<g1, 256, 0, stream>>>(hs1f, hs1b, nullptr,nullptr,nullptr,nullptr,
                                       wx_f, bi_f, xgf, MM, GG, CC);
  sgemm_k<1,1><<<g1, 256, 0, stream>>>(hs1f, hs1b, nullptr,nullptr,nullptr,nullptr,
                                       wx_b, bi_b, xgb, MM, GG, CC);
  gru_layer_k<<<256, 256, 0, stream>>>(xgf, xgb, wh_f, wh_b, br_f, br_b,
                                       hs2f, hs2b, hping, cnt + 2);
  dim3 g2(8, 128);   // N=1024
  sgemm_k<2,0><<<g2, 256, 0, stream>>>(hs2f, hs2b, gam, bet, mu_, var_,
                                       dw, db, logits, MM, VV, CC);
  softmax_k<<<MM, 256, 0, stream>>>(logits);
}

// Round 2
// 8046.146 us; speedup vs baseline: 4.7846x; 4.7846x over previous
//
#include <hip/hip_runtime.h>
#include <hip/hip_fp16.h>

#define BB 32
#define TIN 1024
#define FIN 80
#define CC 512
#define UU 512
#define GG 1536
#define VV 1024
#define TT 512
#define MM (BB*TT)   // 16384
#define EPS 1e-3f
#define NWDIR 128    // workgroups per direction in recurrence

// ---------------- conv1d(stride2,SAME) + bias + relu + BN -> f16 ----------------
__global__ __launch_bounds__(256) void conv_bn_k(
    const float* __restrict__ x, const float* __restrict__ w, const float* __restrict__ cb,
    const float* __restrict__ gam, const float* __restrict__ bet,
    const float* __restrict__ mu_, const float* __restrict__ var_,
    __half* __restrict__ out)
{
  __shared__ float xs[41*80];
  int tg = blockIdx.x;        // 32 groups of 16 t
  int b  = blockIdx.y;
  int ch = blockIdx.z;        // 0/1 channel half
  int t0 = tg*16;
  int in0 = t0*2 - 4;         // SAME pad_left = 4 (pad_total 9)
  for (int i = threadIdx.x; i < 41*80; i += 256) {
    int r = i / 80, f = i - r*80;
    int ri = in0 + r;
    xs[i] = (ri >= 0 && ri < TIN) ? x[((size_t)b*TIN + ri)*FIN + f] : 0.f;
  }
  __syncthreads();
  int c = ch*256 + threadIdx.x;
  float acc[16];
  float bv = cb[c];
#pragma unroll
  for (int i = 0; i < 16; i++) acc[i] = bv;
  for (int k = 0; k < 11; k++) {
    for (int f = 0; f < 80; f++) {
      float wv = w[((size_t)k*80 + f)*CC + c];
#pragma unroll
      for (int i = 0; i < 16; i++) acc[i] += xs[(2*i + k)*80 + f] * wv;
    }
  }
  float ga = gam[c], be = bet[c], mu = mu_[c], iv = rsqrtf(var_[c] + EPS);
#pragma unroll
  for (int i = 0; i < 16; i++) {
    float v = fmaxf(acc[i], 0.f);
    out[((size_t)b*TT + t0 + i)*CC + c] = __float2half(ga*(v - mu)*iv + be);
  }
}

// ---------------- fp32 SGEMM: C(M,N) = op(A)(M,K) @ Bw(K,N) + bias ----------------
// MODE 0: A = A0 ; MODE 1: A = A0+A1 ; MODE 2: A = BN(A0+A1). A stored f16.
// OUTHALF 1: write __half ; 0: write float.
template<int MODE, int OUTHALF>
__global__ __launch_bounds__(256) void sgemm_k(
    const __half* __restrict__ A0, const __half* __restrict__ A1,
    const float* __restrict__ gam, const float* __restrict__ bet,
    const float* __restrict__ mu_, const float* __restrict__ var_,
    const float* __restrict__ Bw, const float* __restrict__ bias,
    void* __restrict__ Cout, int M, int N, int K)
{
  __shared__ float As[8][128];
  __shared__ float Bs[8][128];
  int row0 = blockIdx.y * 128;
  int col0 = blockIdx.x * 128;
  int tid = threadIdx.x;
  int tx = tid & 15, ty = tid >> 4;
  float acc[8][8];
#pragma unroll
  for (int i=0;i<8;i++)
#pragma unroll
    for (int j=0;j<8;j++) acc[i][j]=0.f;
  int ar = tid >> 1;
  int akq = (tid & 1)*4;
  int bkr = tid >> 5;
  int bc = (tid & 31)*4;
  for (int k0 = 0; k0 < K; k0 += 8) {
    size_t aoff = (size_t)(row0+ar)*K + k0 + akq;
    float2 lo = __half22float2(*(const __half2*)(A0 + aoff));
    float2 hi = __half22float2(*(const __half2*)(A0 + aoff + 2));
    float4 a; a.x=lo.x; a.y=lo.y; a.z=hi.x; a.w=hi.y;
    if (MODE >= 1) {
      float2 l1 = __half22float2(*(const __half2*)(A1 + aoff));
      float2 h1 = __half22float2(*(const __half2*)(A1 + aoff + 2));
      a.x+=l1.x; a.y+=l1.y; a.z+=h1.x; a.w+=h1.y;
    }
    if (MODE == 2) {
      int kk = k0 + akq;
      float4 g4 = *(const float4*)(gam+kk);
      float4 b4 = *(const float4*)(bet+kk);
      float4 m4 = *(const float4*)(mu_+kk);
      float4 v4 = *(const float4*)(var_+kk);
      a.x = g4.x*(a.x-m4.x)*rsqrtf(v4.x+EPS)+b4.x;
      a.y = g4.y*(a.y-m4.y)*rsqrtf(v4.y+EPS)+b4.y;
      a.z = g4.z*(a.z-m4.z)*rsqrtf(v4.z+EPS)+b4.z;
      a.w = g4.w*(a.w-m4.w)*rsqrtf(v4.w+EPS)+b4.w;
    }
    As[akq+0][ar]=a.x; As[akq+1][ar]=a.y; As[akq+2][ar]=a.z; As[akq+3][ar]=a.w;
    *(float4*)&Bs[bkr][bc] = *(const float4*)(Bw + (size_t)(k0+bkr)*N + col0 + bc);
    __syncthreads();
#pragma unroll
    for (int kk = 0; kk < 8; kk++) {
      float ar8[8], br8[8];
      *(float4*)&ar8[0] = *(const float4*)&As[kk][ty*8];
      *(float4*)&ar8[4] = *(const float4*)&As[kk][ty*8+4];
      *(float4*)&br8[0] = *(const float4*)&Bs[kk][tx*8];
      *(float4*)&br8[4] = *(const float4*)&Bs[kk][tx*8+4];
#pragma unroll
      for (int i=0;i<8;i++)
#pragma unroll
        for (int j=0;j<8;j++) acc[i][j] += ar8[i]*br8[j];
    }
    __syncthreads();
  }
#pragma unroll
  for (int i=0;i<8;i++) {
    int r = row0 + ty*8 + i;
#pragma unroll
    for (int j=0;j<8;j++) {
      int c2 = col0 + tx*8 + j;
      float v = acc[i][j] + bias[c2];
      if (OUTHALF) ((__half*)Cout)[(size_t)r*N + c2] = __float2half(v);
      else         ((float*)Cout)[(size_t)r*N + c2] = v;
    }
  }
}

// ---------------- persistent bidirectional GRU layer ----------------
// grid = 256 blocks (128 per direction), 256 threads, one block per CU.
// Cross-WG h exchange is done ENTIRELY with device-coherent (sc0 sc1)
// instructions: no __threadfence, no L2 flush anywhere in the step loop.
// Ordering argument: __syncthreads() drains vmcnt(0) for all waves, so by the
// time tid0 bumps the (relaxed, agent-scope) counter, this WG's sc0sc1 h
// stores are at the coherence point; spinners that observe the full count
// then read h with sc0sc1 loads that bypass stale L1/L2.
#define DS_STG(vv, ii) { int b_=(ii)>>7; int k_=((ii)&127)<<2; \
  *(float4*)&hsl[b_][k_ ^ ((b_>>2)<<2)] = vv; }

__global__ __launch_bounds__(256) void gru_layer_k(
    const __half* __restrict__ xgf, const __half* __restrict__ xgb,
    const float* __restrict__ whf, const float* __restrict__ whb,
    const float* __restrict__ brf, const float* __restrict__ brb,
    __half* __restrict__ hsf, __half* __restrict__ hsb,
    float* __restrict__ hping, unsigned int* __restrict__ cnt)
{
  int wg  = blockIdx.x & (NWDIR-1);
  int dir = blockIdx.x >> 7;
  const __half* xg = dir ? xgb : xgf;
  const float* wh  = dir ? whb : whf;
  const float* brc = dir ? brb : brf;
  __half* hs = dir ? hsb : hsf;
  float* hb0 = hping + (size_t)dir * 2 * 32 * 512;   // two ping-pong buffers [b][k]
  unsigned int* c = cnt + dir*16;                    // 64B-separated counters
  int tid = threadIdx.x;
  int u0 = wg * 4;

  __shared__ float Whs[12][516];   // [g*4+uu][k], padded
  __shared__ float hsl[32][512];   // h staged, xor-swizzled by (b>>2)
  __shared__ float S[8][12][33];   // k-partials [kh][col][b]

  for (int i = tid; i < 12*512; i += 256) {
    int cq = i >> 9;
    int k  = i & 511;
    int gcol = (cq>>2)*512 + u0 + (cq&3);
    Whs[cq][k] = wh[(size_t)k*GG + gcol];
  }
  int gb = tid & 31, guu = (tid >> 5) & 3;   // gate-phase mapping (tid<128)
  float brz=0.f, brr=0.f, brh=0.f, hreg=0.f;
  if (tid < 128) {
    int u = u0 + guu;
    brz = brc[u]; brr = brc[512+u]; brh = brc[1024+u];
    // zero ping buffer 0 (h0 = 0), device-coherent so peers see it
    __hip_atomic_store(&hb0[gb*512 + u], 0.f, __ATOMIC_RELAXED, __HIP_MEMORY_SCOPE_AGENT);
  }
  int bq = tid & 7, uu = (tid>>3)&3, kh = tid>>5;  // matmul mapping
  int k0 = kh*64;
  int xorc = bq << 2;

  for (int s = 0; s < 512; s++) {
    __syncthreads();   // drains vmcnt(0): our sc0sc1 h stores are globally visible
    if (tid == 0) {
      __hip_atomic_fetch_add(c, 1u, __ATOMIC_RELAXED, __HIP_MEMORY_SCOPE_AGENT);
      unsigned int tgt = (unsigned int)(s+1) * NWDIR;
      long guard = 0;
      while (__hip_atomic_load(c, __ATOMIC_RELAXED, __HIP_MEMORY_SCOPE_AGENT) < tgt) {
        if (++guard > 50000000L) break;      // deadlock bailout (wrong answer, no hang)
      }
    }
    __syncthreads();
    int p = s & 1;
    const float4* hp4 = (const float4*)(hb0 + p*32*512);
    // stage h -> LDS via device-coherent loads (bypass stale L1/L2), batched
    {
      const float4* a0 = hp4 + tid;
      float4 t0,t1,t2,t3,t4,t5,t6,t7;
      asm volatile(
        "global_load_dwordx4 %0, %8, off sc0 sc1\n\t"
        "global_load_dwordx4 %1, %9, off sc0 sc1\n\t"
        "global_load_dwordx4 %2, %10, off sc0 sc1\n\t"
        "global_load_dwordx4 %3, %11, off sc0 sc1\n\t"
        "global_load_dwordx4 %4, %12, off sc0 sc1\n\t"
        "global_load_dwordx4 %5, %13, off sc0 sc1\n\t"
        "global_load_dwordx4 %6, %14, off sc0 sc1\n\t"
        "global_load_dwordx4 %7, %15, off sc0 sc1\n\t"
        "s_waitcnt vmcnt(0)"
        : "=&v"(t0),"=&v"(t1),"=&v"(t2),"=&v"(t3),
          "=&v"(t4),"=&v"(t5),"=&v"(t6),"=&v"(t7)
        : "v"(a0),"v"(a0+256),"v"(a0+512),"v"(a0+768),
          "v"(a0+1024),"v"(a0+1280),"v"(a0+1536),"v"(a0+1792)
        : "memory");
      DS_STG(t0, tid);      DS_STG(t1, tid+256);  DS_STG(t2, tid+512);  DS_STG(t3, tid+768);
      DS_STG(t4, tid+1024); DS_STG(t5, tid+1280); DS_STG(t6, tid+1536); DS_STG(t7, tid+1792);
      asm volatile(
        "global_load_dwordx4 %0, %8, off sc0 sc1\n\t"
        "global_load_dwordx4 %1, %9, off sc0 sc1\n\t"
        "global_load_dwordx4 %2, %10, off sc0 sc1\n\t"
        "global_load_dwordx4 %3, %11, off sc0 sc1\n\t"
        "global_load_dwordx4 %4, %12, off sc0 sc1\n\t"
        "global_load_dwordx4 %5, %13, off sc0 sc1\n\t"
        "global_load_dwordx4 %6, %14, off sc0 sc1\n\t"
        "global_load_dwordx4 %7, %15, off sc0 sc1\n\t"
        "s_waitcnt vmcnt(0)"
        : "=&v"(t0),"=&v"(t1),"=&v"(t2),"=&v"(t3),
          "=&v"(t4),"=&v"(t5),"=&v"(t6),"=&v"(t7)
        : "v"(a0+2048),"v"(a0+2304),"v"(a0+2560),"v"(a0+2816),
          "v"(a0+3072),"v"(a0+3328),"v"(a0+3584),"v"(a0+3840)
        : "memory");
      DS_STG(t0, tid+2048); DS_STG(t1, tid+2304); DS_STG(t2, tid+2560); DS_STG(t3, tid+2816);
      DS_STG(t4, tid+3072); DS_STG(t5, tid+3328); DS_STG(t6, tid+3584); DS_STG(t7, tid+3840);
    }
    __syncthreads();
    float a0v[4] = {0,0,0,0}, a1v[4] = {0,0,0,0}, a2v[4] = {0,0,0,0};
#pragma unroll 4
    for (int k4 = 0; k4 < 64; k4 += 4) {
      int kk = k0 + k4;
      float4 w0 = *(const float4*)&Whs[uu  ][kk];
      float4 w1 = *(const float4*)&Whs[4+uu][kk];
      float4 w2 = *(const float4*)&Whs[8+uu][kk];
#pragma unroll
      for (int bi = 0; bi < 4; bi++) {
        float4 hv = *(const float4*)&hsl[bq*4+bi][kk ^ xorc];
        a0v[bi] += w0.x*hv.x + w0.y*hv.y + w0.z*hv.z + w0.w*hv.w;
        a1v[bi] += w1.x*hv.x + w1.y*hv.y + w1.z*hv.z + w1.w*hv.w;
        a2v[bi] += w2.x*hv.x + w2.y*hv.y + w2.z*hv.z + w2.w*hv.w;
      }
    }
#pragma unroll
    for (int bi = 0; bi < 4; bi++) {
      S[kh][uu  ][bq*4+bi] = a0v[bi];
      S[kh][4+uu][bq*4+bi] = a1v[bi];
      S[kh][8+uu][bq*4+bi] = a2v[bi];
    }
    __syncthreads();
    if (tid < 128) {
      int u = u0 + guu;
      int t = dir ? (511 - s) : s;
      float rz = brz, rr = brr, rh = brh;
#pragma unroll
      for (int q = 0; q < 8; q++) {
        rz += S[q][guu  ][gb];
        rr += S[q][4+guu][gb];
        rh += S[q][8+guu][gb];
      }
      const __half* xp = xg + ((size_t)gb*TT + t)*GG;
      float xz = __half2float(xp[u]);
      float xr = __half2float(xp[512+u]);
      float xh = __half2float(xp[1024+u]);
      float z = 1.f/(1.f + __expf(-(xz + rz)));
      float r = 1.f/(1.f + __expf(-(xr + rr)));
      float hh = fmaxf(xh + r*rh, 0.f);
      float hn = z*hreg + (1.f - z)*hh;
      hreg = hn;
      // publish for team: device-coherent store (reaches L3, no flush needed)
      __hip_atomic_store(&hb0[(1-p)*32*512 + gb*512 + u], hn,
                         __ATOMIC_RELAXED, __HIP_MEMORY_SCOPE_AGENT);
      hs[((size_t)gb*TT + t)*UU + u] = __float2half(hn); // sequence output (cached ok)
    }
  }
}

// ---------------- row softmax over V=1024, in place ----------------
__global__ __launch_bounds__(256) void softmax_k(float* __restrict__ p) {
  size_t row = blockIdx.x;
  float* pr = p + row*VV;
  int tid = threadIdx.x;
  float4 v = ((float4*)pr)[tid];
  float m = fmaxf(fmaxf(v.x, v.y), fmaxf(v.z, v.w));
#pragma unroll
  for (int o = 32; o >= 1; o >>= 1) m = fmaxf(m, __shfl_xor(m, o));
  __shared__ float red[4];
  __shared__ float red2[4];
  int w = tid >> 6;
  if ((tid & 63) == 0) red[w] = m;
  __syncthreads();
  m = fmaxf(fmaxf(red[0], red[1]), fmaxf(red[2], red[3]));
  v.x = __expf(v.x - m); v.y = __expf(v.y - m);
  v.z = __expf(v.z - m); v.w = __expf(v.w - m);
  float s = v.x + v.y + v.z + v.w;
#pragma unroll
  for (int o = 32; o >= 1; o >>= 1) s += __shfl_xor(s, o);
  if ((tid & 63) == 0) red2[w] = s;
  __syncthreads();
  s = red2[0] + red2[1] + red2[2] + red2[3];
  float inv = 1.f / s;
  v.x *= inv; v.y *= inv; v.z *= inv; v.w *= inv;
  ((float4*)pr)[tid] = v;
}

extern "C" void kernel_launch(void* const* d_in, const int* in_sizes, int n_in,
                              void* d_out, int out_size, void* d_ws, size_t ws_size,
                              hipStream_t stream) {
  const float* x      = (const float*)d_in[0];
  const float* conv_w = (const float*)d_in[1];
  const float* conv_b = (const float*)d_in[2];
  const float* wx_f   = (const float*)d_in[3];
  const float* wh_f   = (const float*)d_in[4];
  const float* bi_f   = (const float*)d_in[5];
  const float* br_f   = (const float*)d_in[6];
  const float* wx_b   = (const float*)d_in[7];
  const float* wh_b   = (const float*)d_in[8];
  const float* bi_b   = (const float*)d_in[9];
  const float* br_b   = (const float*)d_in[10];
  const float* gam    = (const float*)d_in[11];
  const float* bet    = (const float*)d_in[12];
  const float* mu_    = (const float*)d_in[13];
  const float* var_   = (const float*)d_in[14];
  const float* dw     = (const float*)d_in[15];
  const float* db     = (const float*)d_in[16];

  char* ws = (char*)d_ws;
  // layout (bytes)
  __half* c0   = (__half*)(ws + 0);                 // 16,777,216  (conv/BN out; later hs2_f)
  __half* xgf  = (__half*)(ws + 16777216LL);        // 50,331,648
  __half* xgb  = (__half*)(ws + 67108864LL);        // 50,331,648
  __half* hs1f = (__half*)(ws + 117440512LL);       // 16,777,216  (later hs2_b)
  __half* hs1b = (__half*)(ws + 134217728LL);       // 16,777,216
  float*  hping = (float*)(ws + 150994944LL);       // 262,144
  unsigned int* cnt = (unsigned int*)(ws + 151257088LL); // 256 B (4 counters, 64B apart)
  if (ws_size < 151257344ULL) return;               // fail clean rather than corrupt
  __half* hs2f = c0;
  __half* hs2b = hs1f;
  float* logits = (float*)d_out;

  hipMemsetAsync(cnt, 0, 256, stream);              // barrier counters

  dim3 cg(32, 32, 2);
  conv_bn_k<<<cg, 256, 0, stream>>>(x, conv_w, conv_b, gam, bet, mu_, var_, c0);

  dim3 g1(12, 128);  // N/128, M/128 for N=1536
  sgemm_k<0,1><<<g1, 256, 0, stream>>>(c0, nullptr, nullptr,nullptr,nullptr,nullptr,
                                       wx_f, bi_f, xgf, MM, GG, CC);
  sgemm_k<0,1><<<g1, 256, 0, stream>>>(c0, nullptr, nullptr,nullptr,nullptr,nullptr,
                                       wx_b, bi_b, xgb, MM, GG, CC);
  gru_layer_k<<<256, 256, 0, stream>>>(xgf, xgb, wh_f, wh_b, br_f, br_b,
                                       hs1f, hs1b, hping, cnt);
  sgemm_k<1,1><<<g1, 256, 0, stream>>>(hs1f, hs1b, nullptr,nullptr,nullptr,nullptr,
                                       wx_f, bi_f, xgf, MM, GG, CC);
  sgemm_k<1,1><<<g1, 256, 0, stream>>>(hs1f, hs1b, nullptr,nullptr,nullptr,nullptr,
                                       wx_b, bi_b, xgb, MM, GG, CC);
  gru_layer_k<<<256, 256, 0, stream>>>(xgf, xgb, wh_f, wh_b, br_f, br_b,
                                       hs2f, hs2b, hping, cnt + 32);
  dim3 g2(8, 128);   // N=1024
  sgemm_k<2,0><<<g2, 256, 0, stream>>>(hs2f, hs2b, gam, bet, mu_, var_,
                                       dw, db, logits, MM, VV, CC);
  softmax_k<<<MM, 256, 0, stream>>>(logits);
}